// Round 5
// baseline (183.536 us; speedup 1.0000x reference)
//
#include <hip/hip_runtime.h>
#include <hip/hip_bf16.h>

#define NB 4
#define NT 4096
#define NE 768
#define NH 64

using bf16 = __hip_bfloat16;
typedef __attribute__((ext_vector_type(8))) short bf16x8;
typedef __attribute__((ext_vector_type(4))) float f32x4;
typedef __attribute__((ext_vector_type(16))) float f32x16;
typedef __attribute__((ext_vector_type(4))) unsigned int u32x4;

// softmax scale 1/8 with log2(e) folded -> exp2 everywhere
#define QSCALE 0.18033688011112042f /* 0.125 * log2(e) */

__device__ inline short f2bfs(float f) {
  bf16 h = __float2bfloat16(f);
  return __builtin_bit_cast(short, h);
}
__device__ inline float bfs2f(unsigned short u) {
  unsigned v = ((unsigned)u) << 16;
  return __builtin_bit_cast(float, v);
}
__device__ inline unsigned pack_bf2(float a, float b) {
  unsigned short ua = __builtin_bit_cast(unsigned short, __float2bfloat16(a));
  unsigned short ub = __builtin_bit_cast(unsigned short, __float2bfloat16(b));
  return ((unsigned)ub << 16) | ua;
}

#define GLOAD_LDS16(gsrc, ldst)                                        \
  __builtin_amdgcn_global_load_lds(                                    \
      (const __attribute__((address_space(1))) void*)(gsrc),           \
      (__attribute__((address_space(3))) void*)(ldst), 16, 0, 0)

// ---------------- kernel 0: W -> Wt2 fragment layout ----------------------
// Wt2[cbg][ks][lane][8]; j-th elem = W[ks*32+(lane>>4)*8+j][(cbg&3)*16+(lane&15)]
__global__ __launch_bounds__(256) void k_wt(const float* __restrict__ Wk,
                                            const float* __restrict__ Wq,
                                            const float* __restrict__ Wv,
                                            bf16* __restrict__ Wt2) {
  __shared__ float xl[32][65];
  const int m = blockIdx.x / 24;
  const int ks = blockIdx.x % 24;
  const int tid = threadIdx.x;
  const float* W = (m == 0) ? Wk : ((m == 1) ? Wq : Wv);
  const float scale = (m == 1) ? QSCALE : 1.0f;
  const int e0 = ks * 32;
#pragma unroll
  for (int i = 0; i < 8; ++i) {
    const int lin = i * 256 + tid;
    xl[lin >> 6][lin & 63] = W[(size_t)(e0 + (lin >> 6)) * NH + (lin & 63)];
  }
  __syncthreads();
  const int lane = tid & 63, w = tid >> 6;
  const int cbg = m * 4 + w;
  bf16x8 t;
#pragma unroll
  for (int j = 0; j < 8; ++j)
    t[j] = f2bfs(xl[((lane >> 4) << 3) + j][w * 16 + (lane & 15)] * scale);
  *reinterpret_cast<bf16x8*>(Wt2 + (((size_t)cbg * 24 + ks) * 64 + lane) * 8) = t;
}

// ---------------- kernel 1: fused Q/K/V projections -----------------------
// 512 blocks x 256 thr; block = 32-row x-stripe in LDS (swizzled); wave w
// computes cbg w*3..w*3+2 for BOTH 16-row stripes (1 W-load feeds 2 MFMA).
__global__ __launch_bounds__(256) void k_proj(const float* __restrict__ x,
                                              const bf16* __restrict__ Wt2,
                                              bf16* __restrict__ Q,
                                              bf16* __restrict__ K,
                                              bf16* __restrict__ Vt) {
  __shared__ __align__(16) bf16 xl[32][768];  // 48 KB
  const int tid = threadIdx.x;
  const int wave = tid >> 6, lane = tid & 63;
  const int lr = lane & 15, lk = lane >> 4;
  const int row0 = blockIdx.x * 32;

#pragma unroll
  for (int j = 0; j < 12; ++j) {
    const int e = (j * 256 + tid) * 8;
    const int row = e / 768;
    const int col = e - row * 768;
    const int chunk = col >> 3;
    const int sch = (chunk & ~7) | ((chunk ^ row) & 7);
    const float* xp = x + (size_t)(row0 + row) * NE + col;
    float4 a0 = *reinterpret_cast<const float4*>(xp);
    float4 a1 = *reinterpret_cast<const float4*>(xp + 4);
    bf16x8 af;
    af[0] = f2bfs(a0.x); af[1] = f2bfs(a0.y); af[2] = f2bfs(a0.z); af[3] = f2bfs(a0.w);
    af[4] = f2bfs(a1.x); af[5] = f2bfs(a1.y); af[6] = f2bfs(a1.z); af[7] = f2bfs(a1.w);
    *reinterpret_cast<bf16x8*>((char*)xl + row * 1536 + sch * 16) = af;
  }
  __syncthreads();

  f32x4 acc0[3], acc1[3];
#pragma unroll
  for (int cb = 0; cb < 3; ++cb)
#pragma unroll
    for (int r = 0; r < 4; ++r) { acc0[cb][r] = 0.f; acc1[cb][r] = 0.f; }

#pragma unroll 4
  for (int ks = 0; ks < 24; ++ks) {
    const int chunk = ks * 4 + lk;
    const int sch = (chunk & ~7) | ((chunk ^ lr) & 7);
    bf16x8 af0 = *reinterpret_cast<const bf16x8*>((const char*)xl + lr * 1536 + sch * 16);
    bf16x8 af1 = *reinterpret_cast<const bf16x8*>((const char*)xl + (16 + lr) * 1536 + sch * 16);
#pragma unroll
    for (int cb = 0; cb < 3; ++cb) {
      bf16x8 bfr = *reinterpret_cast<const bf16x8*>(
          Wt2 + (((size_t)(wave * 3 + cb) * 24 + ks) * 64 + lane) * 8);
      acc0[cb] = __builtin_amdgcn_mfma_f32_16x16x32_bf16(af0, bfr, acc0[cb], 0, 0, 0);
      acc1[cb] = __builtin_amdgcn_mfma_f32_16x16x32_bf16(af1, bfr, acc1[cb], 0, 0, 0);
    }
  }

#pragma unroll
  for (int st = 0; st < 2; ++st) {
    const int trow = row0 + st * 16 + lk * 4;
#pragma unroll
    for (int cb = 0; cb < 3; ++cb) {
      const f32x4 a = st ? acc1[cb] : acc0[cb];
      const int hh0 = (wave * 3 + cb) * 16;
      const int m = hh0 >> 6;
      const int h = (hh0 & 63) + lr;
      if (m == 0) {
#pragma unroll
        for (int r = 0; r < 4; ++r)
          K[(size_t)(trow + r) * NH + h] = __float2bfloat16(a[r]);
      } else if (m == 1) {
#pragma unroll
        for (int r = 0; r < 4; ++r)
          Q[(size_t)(trow + r) * NH + h] = __float2bfloat16(a[r]);
      } else {
        const int bb = trow >> 12;
        const int t = trow & (NT - 1);
        ushort4 pk;
        pk.x = (unsigned short)f2bfs(a[0]);
        pk.y = (unsigned short)f2bfs(a[1]);
        pk.z = (unsigned short)f2bfs(a[2]);
        pk.w = (unsigned short)f2bfs(a[3]);
        *reinterpret_cast<ushort4*>(Vt + (size_t)(bb * NH + h) * NT + t) = pk;
      }
    }
  }
}

// ---------------- kernel 2a: split-KV flash attention (pipelined) ---------
// Block = 4 waves x 32 q-rows = 128-row stripe. K triple-buffered, V double-
// buffered in LDS. QK^T of tile i+1 (MFMA) overlaps softmax of tile i (VALU).
__device__ inline void stage_k(const bf16* Kb, int k0, bf16* Kd, int wave, int lane) {
  const int rsub = lane >> 3, ch = lane & 7;
#pragma unroll
  for (int j = 0; j < 2; ++j) {
    const int br = j * 32 + wave * 8;
    const int row = br + rsub;
    const int sch = ch ^ (row & 7);
    GLOAD_LDS16(Kb + (size_t)(k0 + row) * NH + sch * 8, Kd + br * 64);
  }
}
__device__ inline void stage_v(const bf16* Vb, int k0, bf16* Vd, int wave, int lane) {
  const int rsub = lane >> 3, ch = lane & 7;
#pragma unroll
  for (int j = 0; j < 2; ++j) {
    const int br = j * 32 + wave * 8;
    const int row = br + rsub;
    const int sch = ch ^ (row & 7);
    GLOAD_LDS16(Vb + (size_t)row * NT + k0 + sch * 8, Vd + br * 64);
  }
}

// QK^T for one 64-key tile into SA (f32x16[2]); includes causal mask.
#define QK_TILE(SA, KBUF, KT)                                                 \
  {                                                                           \
    const bf16* kbp_ = (KBUF);                                                \
    _Pragma("unroll")                                                         \
    for (int kb = 0; kb < 2; ++kb) {                                          \
      _Pragma("unroll") for (int r = 0; r < 16; ++r) SA[kb][r] = 0.f;         \
      __builtin_amdgcn_s_setprio(1);                                          \
      _Pragma("unroll")                                                       \
      for (int ks = 0; ks < 4; ++ks) {                                        \
        const int row_ = l31 + 32 * kb;                                       \
        const int sch_ = (hi5 + 2 * ks) ^ (row_ & 7);                         \
        bf16x8 kf_ = *reinterpret_cast<const bf16x8*>(kbp_ + row_ * 64 + sch_ * 8); \
        SA[kb] = __builtin_amdgcn_mfma_f32_32x32x16_bf16(kf_, qf[ks], SA[kb], 0, 0, 0); \
      }                                                                       \
      __builtin_amdgcn_s_setprio(0);                                          \
    }                                                                         \
    if ((KT) >= 2 * s) {                                                      \
      _Pragma("unroll")                                                       \
      for (int kb = 0; kb < 2; ++kb)                                          \
        _Pragma("unroll") for (int r = 0; r < 16; ++r) {                      \
          const int kg_ = (KT) * 64 + (r & 3) + 8 * (r >> 2) + 4 * hi5 + 32 * kb; \
          if (kg_ > qcol) SA[kb][r] = -1e30f;                                 \
        }                                                                     \
    }                                                                         \
  }

// one pipeline step: barrier; prefetch K[i+2],V[i+1]; QK(i+1)->SN; softmax+PV(i) on SC
#define TILE_BODY(SC, SN, I)                                                  \
  {                                                                           \
    __syncthreads();                                                          \
    if ((I) + 2 < n) stage_k(Kb, (kt0 + (I) + 2) * 64, &Kl[((I) + 2) % 3][0][0], wave, lane); \
    if ((I) + 1 < n) {                                                        \
      stage_v(Vb, (kt0 + (I) + 1) * 64, &Vl[((I) + 1) & 1][0][0], wave, lane); \
      QK_TILE(SN, &Kl[((I) + 1) % 3][0][0], kt0 + (I) + 1);                   \
    }                                                                         \
    /* softmax of SC (VALU; overlaps SN's MFMAs) */                           \
    float t0_[8];                                                             \
    _Pragma("unroll")                                                         \
    for (int r = 0; r < 8; ++r)                                               \
      t0_[r] = fmaxf(fmaxf(SC[0][r], SC[0][r + 8]), fmaxf(SC[1][r], SC[1][r + 8])); \
    float pm = fmaxf(fmaxf(fmaxf(t0_[0], t0_[1]), fmaxf(t0_[2], t0_[3])),     \
                     fmaxf(fmaxf(t0_[4], t0_[5]), fmaxf(t0_[6], t0_[7])));    \
    pm = fmaxf(pm, __shfl_xor(pm, 32));                                       \
    if (!__all(pm - m <= 6.f)) {                                              \
      const float mn = fmaxf(m, pm);                                          \
      const float alpha = exp2f(m - mn);                                      \
      lsum *= alpha;                                                          \
      _Pragma("unroll")                                                       \
      for (int hb = 0; hb < 2; ++hb)                                          \
        _Pragma("unroll") for (int r = 0; r < 16; ++r) o[hb][r] *= alpha;     \
      m = mn;                                                                 \
    }                                                                         \
    float rs0 = 0.f, rs1 = 0.f, rs2 = 0.f, rs3 = 0.f;                         \
    _Pragma("unroll")                                                         \
    for (int kb = 0; kb < 2; ++kb)                                            \
      _Pragma("unroll") for (int r = 0; r < 16; r += 4) {                     \
        SC[kb][r] = exp2f(SC[kb][r] - m); rs0 += SC[kb][r];                   \
        SC[kb][r + 1] = exp2f(SC[kb][r + 1] - m); rs1 += SC[kb][r + 1];       \
        SC[kb][r + 2] = exp2f(SC[kb][r + 2] - m); rs2 += SC[kb][r + 2];       \
        SC[kb][r + 3] = exp2f(SC[kb][r + 3] - m); rs3 += SC[kb][r + 3];       \
      }                                                                       \
    float rs = (rs0 + rs1) + (rs2 + rs3);                                     \
    rs += __shfl_xor(rs, 32);                                                 \
    lsum += rs;                                                               \
    unsigned pk[2][4][2];                                                     \
    _Pragma("unroll")                                                         \
    for (int kb = 0; kb < 2; ++kb)                                            \
      _Pragma("unroll") for (int q4 = 0; q4 < 4; ++q4)                        \
        _Pragma("unroll") for (int p = 0; p < 2; ++p)                         \
          pk[kb][q4][p] = pack_bf2(SC[kb][4 * q4 + 2 * p], SC[kb][4 * q4 + 2 * p + 1]); \
    const bf16* Vlb_ = &Vl[(I) & 1][0][0];                                    \
    _Pragma("unroll")                                                         \
    for (int kb16 = 0; kb16 < 4; ++kb16) {                                    \
      const int kb32 = kb16 >> 1;                                             \
      const int q4a = 2 * (kb16 & 1);                                         \
      const unsigned X0 = pk[kb32][q4a][0], X1 = pk[kb32][q4a][1];            \
      const unsigned Y0 = pk[kb32][q4a + 1][0], Y1 = pk[kb32][q4a + 1][1];    \
      const unsigned pX0 = __shfl_xor((int)X0, 32), pX1 = __shfl_xor((int)X1, 32); \
      const unsigned pY0 = __shfl_xor((int)Y0, 32), pY1 = __shfl_xor((int)Y1, 32); \
      u32x4 pw;                                                               \
      pw[0] = hi5 ? pY0 : X0;                                                 \
      pw[1] = hi5 ? pY1 : X1;                                                 \
      pw[2] = hi5 ? Y0 : pX0;                                                 \
      pw[3] = hi5 ? Y1 : pX1;                                                 \
      const bf16x8 pf = __builtin_bit_cast(bf16x8, pw);                       \
      __builtin_amdgcn_s_setprio(1);                                          \
      _Pragma("unroll")                                                       \
      for (int hb = 0; hb < 2; ++hb) {                                        \
        const int row_ = l31 + 32 * hb;                                       \
        const int sch_ = (hi5 + 2 * kb16) ^ (row_ & 7);                       \
        bf16x8 vf = *reinterpret_cast<const bf16x8*>(Vlb_ + row_ * 64 + sch_ * 8); \
        o[hb] = __builtin_amdgcn_mfma_f32_32x32x16_bf16(vf, pf, o[hb], 0, 0, 0); \
      }                                                                       \
      __builtin_amdgcn_s_setprio(0);                                          \
    }                                                                         \
  }

__global__ __launch_bounds__(256) void k_attn_part(const bf16* __restrict__ Q,
                                                   const bf16* __restrict__ K,
                                                   const bf16* __restrict__ Vt,
                                                   bf16* __restrict__ part_o,
                                                   float* __restrict__ part_ml,
                                                   int CH, int MAXC) {
  __shared__ __align__(16) bf16 Kl[3][64][64];  // 24 KB
  __shared__ __align__(16) bf16 Vl[2][64][64];  // 16 KB
  const int tid = threadIdx.x;
  const int wave = tid >> 6, lane = tid & 63;
  const int l31 = lane & 31, hi5 = lane >> 5;
  const int gid = blockIdx.x;
  const int c = gid % MAXC;
  const int srs = (gid / MAXC) & 31;
  const int b = gid / (MAXC * 32);
  const int s = 31 - srs;  // big stripes dispatched first
  const int ntiles = 2 * s + 2;
  const int nch = (ntiles + CH - 1) / CH;
  if (c >= nch) return;
  const int kt0 = c * CH;
  const int n = min(CH, ntiles - kt0);
  const int qblk = s * 128;
  const int qrow = 8 * wave + (l31 & 7) + 32 * (l31 >> 3);  // 0..127
  const int qcol = qblk + qrow;

  const bf16* Qb = Q + (size_t)(b * NT + qcol) * NH;
  const bf16* Kb = K + (size_t)b * NT * NH;
  const bf16* Vb = Vt + (size_t)b * NH * NT;

  bf16x8 qf[4];
#pragma unroll
  for (int ks = 0; ks < 4; ++ks)
    qf[ks] = *reinterpret_cast<const bf16x8*>(Qb + ks * 16 + hi5 * 8);

  f32x16 o[2];
#pragma unroll
  for (int hb = 0; hb < 2; ++hb)
#pragma unroll
    for (int r = 0; r < 16; ++r) o[hb][r] = 0.f;
  float m = -1e30f, lsum = 0.f;

  // prologue: tile 0 staged+computed; tile 1 staging in flight
  stage_k(Kb, kt0 * 64, &Kl[0][0][0], wave, lane);
  stage_v(Vb, kt0 * 64, &Vl[0][0][0], wave, lane);
  __syncthreads();
  if (n > 1) stage_k(Kb, (kt0 + 1) * 64, &Kl[1][0][0], wave, lane);
  f32x16 saA[2], saB[2];
  QK_TILE(saA, &Kl[0][0][0], kt0);

  int i = 0;
  for (;;) {
    TILE_BODY(saA, saB, i); if (++i >= n) break;
    TILE_BODY(saB, saA, i); if (++i >= n) break;
  }

  // ---- store partials: po bf16[128][64], pml f32[2][128]
  const size_t idx = (size_t)(b * 32 + s) * MAXC + c;
  bf16* po = part_o + idx * (128 * 64);
#pragma unroll
  for (int hb = 0; hb < 2; ++hb)
#pragma unroll
    for (int q4 = 0; q4 < 4; ++q4) {
      const int h0 = 32 * hb + 8 * q4 + 4 * hi5;
      ushort4 pk4;
      pk4.x = (unsigned short)f2bfs(o[hb][4 * q4 + 0]);
      pk4.y = (unsigned short)f2bfs(o[hb][4 * q4 + 1]);
      pk4.z = (unsigned short)f2bfs(o[hb][4 * q4 + 2]);
      pk4.w = (unsigned short)f2bfs(o[hb][4 * q4 + 3]);
      *reinterpret_cast<ushort4*>(po + (size_t)qrow * 64 + h0) = pk4;
    }
  if (hi5 == 0) {
    float* pml = part_ml + idx * 256;
    pml[qrow] = m;
    pml[128 + qrow] = lsum;
  }
}

// ---------------- kernel 2b: combine + normalize --------------------------
// grid NB*32*8 x 256 thr; block = 16 rows; thread = (row, 4-col group)
__global__ __launch_bounds__(256) void k_attn_comb(const bf16* __restrict__ part_o,
                                                   const float* __restrict__ part_ml,
                                                   float* __restrict__ out,
                                                   int CH, int MAXC) {
  const int gid = blockIdx.x;
  const int rg = gid & 7;
  const int s = (gid >> 3) & 31;
  const int b = gid >> 8;
  const int row = rg * 16 + (threadIdx.x >> 4);
  const int cq = threadIdx.x & 15;
  const int ntiles = 2 * s + 2;
  const int nc = (ntiles + CH - 1) / CH;
  const size_t base = (size_t)(b * 32 + s) * MAXC;

  float M = -1e30f;
  for (int c = 0; c < nc; ++c)
    M = fmaxf(M, part_ml[(base + c) * 256 + row]);
  float L = 0.f, a0 = 0.f, a1 = 0.f, a2 = 0.f, a3 = 0.f;
  for (int c = 0; c < nc; ++c) {
    const float mc = part_ml[(base + c) * 256 + row];
    const float lc = part_ml[(base + c) * 256 + 128 + row];
    const float sc = exp2f(mc - M);
    L += lc * sc;
    ushort4 v = *reinterpret_cast<const ushort4*>(
        part_o + (base + c) * (128 * 64) + (size_t)row * 64 + cq * 4);
    a0 += bfs2f(v.x) * sc;
    a1 += bfs2f(v.y) * sc;
    a2 += bfs2f(v.z) * sc;
    a3 += bfs2f(v.w) * sc;
  }
  const float inv = 1.f / L;
  float4 ov;
  ov.x = a0 * inv; ov.y = a1 * inv; ov.z = a2 * inv; ov.w = a3 * inv;
  *reinterpret_cast<float4*>(
      out + (size_t)(b * NT + s * 128 + row) * NH + cq * 4) = ov;
}

// ---------------- launcher ------------------------------------------------
extern "C" void kernel_launch(void* const* d_in, const int* in_sizes, int n_in,
                              void* d_out, int out_size, void* d_ws, size_t ws_size,
                              hipStream_t stream) {
  const float* x  = (const float*)d_in[0];
  const float* Wk = (const float*)d_in[1];
  const float* Wq = (const float*)d_in[2];
  const float* Wv = (const float*)d_in[3];
  float* out = (float*)d_out;

  char* ws = (char*)d_ws;
  const size_t sz_wt  = (size_t)3 * NH * NE * sizeof(bf16);
  const size_t sz_qkv = (size_t)NB * NT * NH * sizeof(bf16);
  const size_t off_q  = (sz_wt + 255) & ~size_t(255);
  const size_t off_k  = off_q + sz_qkv;
  const size_t off_vt = off_k + sz_qkv;
  const size_t off_pp = off_vt + sz_qkv;

  // per-chunk partial: o bf16[128][64] + ml f32[2][128]
  const size_t per_chunk = (size_t)128 * 64 * sizeof(bf16) + 256 * sizeof(float);
  int CH = 64, MAXC = 1;
  const int opts_ch[3]   = {6, 8, 16};
  const int opts_maxc[3] = {11, 8, 4};
  for (int i = 0; i < 3; ++i) {
    const size_t need = off_pp + (size_t)NB * 32 * opts_maxc[i] * per_chunk;
    if (ws_size >= need) { CH = opts_ch[i]; MAXC = opts_maxc[i]; break; }
  }
  const size_t n_idx = (size_t)NB * 32 * MAXC;
  const size_t off_po = off_pp;
  const size_t off_ml = off_po + n_idx * (size_t)(128 * 64) * sizeof(bf16);

  bf16* Wt2 = (bf16*)(ws);
  bf16* Qw  = (bf16*)(ws + off_q);
  bf16* Kw  = (bf16*)(ws + off_k);
  bf16* Vtw = (bf16*)(ws + off_vt);
  bf16* part_o   = (bf16*)(ws + off_po);
  float* part_ml = (float*)(ws + off_ml);

  hipLaunchKernelGGL(k_wt, dim3(3 * 24), dim3(256), 0, stream, Wk, Wq, Wv, Wt2);
  hipLaunchKernelGGL(k_proj, dim3(NB * NT / 32), dim3(256), 0, stream,
                     x, Wt2, Qw, Kw, Vtw);
  hipLaunchKernelGGL(k_attn_part, dim3(NB * 32 * MAXC), dim3(256), 0, stream,
                     Qw, Kw, Vtw, part_o, part_ml, CH, MAXC);
  hipLaunchKernelGGL(k_attn_comb, dim3(NB * 32 * 8), dim3(256), 0, stream,
                     part_o, part_ml, out, CH, MAXC);
}

// Round 6
// 178.996 us; speedup vs baseline: 1.0254x; 1.0254x over previous
//
#include <hip/hip_runtime.h>
#include <hip/hip_bf16.h>

#define NB 4
#define NT 4096
#define NE 768
#define NH 64

using bf16 = __hip_bfloat16;
typedef __attribute__((ext_vector_type(8))) short bf16x8;
typedef __attribute__((ext_vector_type(4))) float f32x4;
typedef __attribute__((ext_vector_type(16))) float f32x16;
typedef __attribute__((ext_vector_type(4))) unsigned int u32x4;

// softmax scale 1/8 with log2(e) folded -> exp2 everywhere
#define QSCALE 0.18033688011112042f /* 0.125 * log2(e) */

__device__ inline short f2bfs(float f) {
  bf16 h = __float2bfloat16(f);
  return __builtin_bit_cast(short, h);
}
__device__ inline float bfs2f(unsigned short u) {
  unsigned v = ((unsigned)u) << 16;
  return __builtin_bit_cast(float, v);
}
__device__ inline unsigned pack_bf2(float a, float b) {
  unsigned short ua = __builtin_bit_cast(unsigned short, __float2bfloat16(a));
  unsigned short ub = __builtin_bit_cast(unsigned short, __float2bfloat16(b));
  return ((unsigned)ub << 16) | ua;
}

#define GLOAD_LDS16(gsrc, ldst)                                        \
  __builtin_amdgcn_global_load_lds(                                    \
      (const __attribute__((address_space(1))) void*)(gsrc),           \
      (__attribute__((address_space(3))) void*)(ldst), 16, 0, 0)

// ---------------- kernel 0: prep ------------------------------------------
// blocks 0..71: W -> Wt2 fragment layout (Wt2[cbg][ks][lane][8]).
// blocks 72.. : x f32 -> bf16, 16B-chunk swizzled within each row
//               (chunk' = (chunk&~7)|((chunk^t)&7)) so k_proj can stage
//               linearly with global_load_lds yet read conflict-free.
__global__ __launch_bounds__(256) void k_prep(const float* __restrict__ x,
                                              const float* __restrict__ Wk,
                                              const float* __restrict__ Wq,
                                              const float* __restrict__ Wv,
                                              bf16* __restrict__ Wt2,
                                              bf16* __restrict__ xb) {
  __shared__ float wl[32][65];
  const int tid = threadIdx.x;
  if (blockIdx.x < 72) {
    const int m = blockIdx.x / 24;
    const int ks = blockIdx.x % 24;
    const float* W = (m == 0) ? Wk : ((m == 1) ? Wq : Wv);
    const float scale = (m == 1) ? QSCALE : 1.0f;
#pragma unroll
    for (int i = 0; i < 8; ++i) {
      const int lin = i * 256 + tid;
      wl[lin >> 6][lin & 63] = W[(size_t)(ks * 32 + (lin >> 6)) * NH + (lin & 63)];
    }
    __syncthreads();
    const int lane = tid & 63, w = tid >> 6;
    const int cbg = m * 4 + w;
    bf16x8 t;
#pragma unroll
    for (int j = 0; j < 8; ++j)
      t[j] = f2bfs(wl[((lane >> 4) << 3) + j][w * 16 + (lane & 15)] * scale);
    *reinterpret_cast<bf16x8*>(Wt2 + (((size_t)cbg * 24 + ks) * 64 + lane) * 8) = t;
    return;
  }
  // x conversion: 2048 elems per block
  const size_t e0 = ((size_t)(blockIdx.x - 72) * 256 + tid) * 8;
  const int row = (int)(e0 / 768);
  const int col = (int)(e0 - (size_t)row * 768);
  const int chunk = col >> 3;
  const int sch = (chunk & ~7) | ((chunk ^ row) & 7);
  float4 a0 = *reinterpret_cast<const float4*>(x + e0);
  float4 a1 = *reinterpret_cast<const float4*>(x + e0 + 4);
  bf16x8 af;
  af[0] = f2bfs(a0.x); af[1] = f2bfs(a0.y); af[2] = f2bfs(a0.z); af[3] = f2bfs(a0.w);
  af[4] = f2bfs(a1.x); af[5] = f2bfs(a1.y); af[6] = f2bfs(a1.z); af[7] = f2bfs(a1.w);
  *reinterpret_cast<bf16x8*>(xb + (size_t)row * 768 + sch * 8) = af;
}

// ---------------- kernel 1: fused Q/K/V projections -----------------------
// grid (256, 3): blockIdx.x = 64-row group, blockIdx.y = m. 4 waves = 4
// 16-col blocks; each wave holds its 24 W-fragments in registers (96 VGPR).
// x staged via global_load_lds (zero VALU; swizzle pre-baked in xb).
__global__ __launch_bounds__(256) void k_proj(const bf16* __restrict__ xb,
                                              const bf16* __restrict__ Wt2,
                                              bf16* __restrict__ Q,
                                              bf16* __restrict__ K,
                                              bf16* __restrict__ Vt) {
  __shared__ __align__(16) bf16 xl[32][768];  // 48 KB
  const int tid = threadIdx.x;
  const int wave = tid >> 6, lane = tid & 63;
  const int lr = lane & 15, lk = lane >> 4;
  const int m = blockIdx.y;
  const int cbg = m * 4 + wave;

  bf16x8 wf[24];
#pragma unroll
  for (int ks = 0; ks < 24; ++ks)
    wf[ks] = *reinterpret_cast<const bf16x8*>(
        Wt2 + (((size_t)cbg * 24 + ks) * 64 + lane) * 8);

  for (int grp = 0; grp < 2; ++grp) {
    const int t0 = blockIdx.x * 64 + grp * 32;
#pragma unroll
    for (int i = 0; i < 12; ++i)
      GLOAD_LDS16(xb + (size_t)t0 * 768 + ((size_t)i * 256 + tid) * 8,
                  (char*)xl + (i * 256 + tid) * 16);
    __syncthreads();

    f32x4 a0, a1;
#pragma unroll
    for (int r = 0; r < 4; ++r) { a0[r] = 0.f; a1[r] = 0.f; }
#pragma unroll
    for (int ks = 0; ks < 24; ++ks) {
      const int chunk = ks * 4 + lk;
      const int sch = (chunk & ~7) | ((chunk ^ lr) & 7);  // (16+lr)&7 == lr&7
      bf16x8 af0 = *reinterpret_cast<const bf16x8*>((const char*)xl + lr * 1536 + sch * 16);
      bf16x8 af1 = *reinterpret_cast<const bf16x8*>((const char*)xl + (16 + lr) * 1536 + sch * 16);
      a0 = __builtin_amdgcn_mfma_f32_16x16x32_bf16(af0, wf[ks], a0, 0, 0, 0);
      a1 = __builtin_amdgcn_mfma_f32_16x16x32_bf16(af1, wf[ks], a1, 0, 0, 0);
    }

#pragma unroll
    for (int sub = 0; sub < 2; ++sub) {
      const f32x4 a = sub ? a1 : a0;
      const int trow = t0 + sub * 16 + lk * 4;
      const int h = wave * 16 + lr;
      if (m == 0) {
#pragma unroll
        for (int r = 0; r < 4; ++r)
          K[(size_t)(trow + r) * NH + h] = __float2bfloat16(a[r]);
      } else if (m == 1) {
#pragma unroll
        for (int r = 0; r < 4; ++r)
          Q[(size_t)(trow + r) * NH + h] = __float2bfloat16(a[r]);
      } else {
        const int bb = trow >> 12;
        const int t = trow & (NT - 1);
        ushort4 pk4;
        pk4.x = (unsigned short)f2bfs(a[0]);
        pk4.y = (unsigned short)f2bfs(a[1]);
        pk4.z = (unsigned short)f2bfs(a[2]);
        pk4.w = (unsigned short)f2bfs(a[3]);
        *reinterpret_cast<ushort4*>(Vt + (size_t)(bb * NH + h) * NT + t) = pk4;
      }
    }
    __syncthreads();  // LDS reads done before next group restages
  }
}

// ---------------- kernel 2a: split-KV flash attention (no LDS, no bar) ----
// Unit = ONE WAVE = (batch, 32-row q-stripe, chunk of CH 64-key tiles).
// K/V fragments straight from L2; P in registers; in-lane softmax.
__global__ __launch_bounds__(256) void k_attn_part(const bf16* __restrict__ Q,
                                                   const bf16* __restrict__ K,
                                                   const bf16* __restrict__ Vt,
                                                   bf16* __restrict__ part_o,
                                                   float* __restrict__ part_ml,
                                                   int CH, int MAXC) {
  const int tid = threadIdx.x;
  const int wave = tid >> 6, lane = tid & 63;
  const int l31 = lane & 31, hi5 = lane >> 5;
  const int unit = blockIdx.x * 4 + wave;
  const int c = unit % MAXC;
  const int srs = (unit / MAXC) & 127;
  const int b = unit / (MAXC * 128);
  const int s = 127 - srs;  // big stripes dispatched first
  const int ntiles = (s >> 1) + 1;
  const int nch = (ntiles + CH - 1) / CH;
  if (c >= nch) return;  // no barriers anywhere: early exit is safe
  const int kt0c = c * CH;
  const int ktend = min(kt0c + CH, ntiles);
  const int qblk = s * 32;
  const int qcol = qblk + l31;

  const bf16* Qb = Q + (size_t)(b * NT + qcol) * NH;
  const bf16* Kb = K + (size_t)b * NT * NH;
  const bf16* Vb = Vt + (size_t)b * NH * NT;

  bf16x8 qf[4];
#pragma unroll
  for (int ks = 0; ks < 4; ++ks)
    qf[ks] = *reinterpret_cast<const bf16x8*>(Qb + ks * 16 + hi5 * 8);

  f32x16 o[2];
#pragma unroll
  for (int hb = 0; hb < 2; ++hb)
#pragma unroll
    for (int r = 0; r < 16; ++r) o[hb][r] = 0.f;
  float m = -1e30f, lsum = 0.f;

  for (int kt = kt0c; kt < ktend; ++kt) {
    const int k0 = kt * 64;
    // ---- issue K fragments (A-operand: 32 keys x 16 h per slice)
    bf16x8 kf[2][4];
#pragma unroll
    for (int kb = 0; kb < 2; ++kb)
#pragma unroll
      for (int ks = 0; ks < 4; ++ks)
        kf[kb][ks] = *reinterpret_cast<const bf16x8*>(
            Kb + (size_t)(k0 + 32 * kb + l31) * NH + ks * 16 + hi5 * 8);
    // ---- issue V fragments early (consumed after softmax)
    bf16x8 vf[4][2];
#pragma unroll
    for (int kb16 = 0; kb16 < 4; ++kb16)
#pragma unroll
      for (int hb = 0; hb < 2; ++hb)
        vf[kb16][hb] = *reinterpret_cast<const bf16x8*>(
            Vb + (size_t)(l31 + 32 * hb) * NT + k0 + kb16 * 16 + hi5 * 8);

    // ---- S^T = K Q^T  (D[key][q])
    f32x16 sa[2];
#pragma unroll
    for (int kb = 0; kb < 2; ++kb) {
#pragma unroll
      for (int r = 0; r < 16; ++r) sa[kb][r] = 0.f;
      __builtin_amdgcn_s_setprio(1);
#pragma unroll
      for (int ks = 0; ks < 4; ++ks)
        sa[kb] = __builtin_amdgcn_mfma_f32_32x32x16_bf16(kf[kb][ks], qf[ks], sa[kb], 0, 0, 0);
      __builtin_amdgcn_s_setprio(0);
    }
    // ---- causal mask (diagonal tile only)
    if (kt == ntiles - 1) {
#pragma unroll
      for (int kb = 0; kb < 2; ++kb)
#pragma unroll
        for (int r = 0; r < 16; ++r) {
          const int kg = k0 + (r & 3) + 8 * (r >> 2) + 4 * hi5 + 32 * kb;
          if (kg > qcol) sa[kb][r] = -1e30f;
        }
    }
    // ---- in-lane softmax (keys split across lane, lane^32)
    float t0[8];
#pragma unroll
    for (int r = 0; r < 8; ++r)
      t0[r] = fmaxf(fmaxf(sa[0][r], sa[0][r + 8]), fmaxf(sa[1][r], sa[1][r + 8]));
    float pm = fmaxf(fmaxf(fmaxf(t0[0], t0[1]), fmaxf(t0[2], t0[3])),
                     fmaxf(fmaxf(t0[4], t0[5]), fmaxf(t0[6], t0[7])));
    pm = fmaxf(pm, __shfl_xor(pm, 32));
    if (!__all(pm - m <= 6.f)) {  // defer-max
      const float mn = fmaxf(m, pm);
      const float alpha = exp2f(m - mn);
      lsum *= alpha;
#pragma unroll
      for (int hb = 0; hb < 2; ++hb)
#pragma unroll
        for (int r = 0; r < 16; ++r) o[hb][r] *= alpha;
      m = mn;
    }
    float rs0 = 0.f, rs1 = 0.f, rs2 = 0.f, rs3 = 0.f;
#pragma unroll
    for (int kb = 0; kb < 2; ++kb)
#pragma unroll
      for (int r = 0; r < 16; r += 4) {
        sa[kb][r] = exp2f(sa[kb][r] - m); rs0 += sa[kb][r];
        sa[kb][r + 1] = exp2f(sa[kb][r + 1] - m); rs1 += sa[kb][r + 1];
        sa[kb][r + 2] = exp2f(sa[kb][r + 2] - m); rs2 += sa[kb][r + 2];
        sa[kb][r + 3] = exp2f(sa[kb][r + 3] - m); rs3 += sa[kb][r + 3];
      }
    float rs = (rs0 + rs1) + (rs2 + rs3);
    rs += __shfl_xor(rs, 32);
    lsum += rs;
    // ---- pack P to bf16 pairs; redistribute halves via shfl_xor(32)
    unsigned pk[2][4][2];
#pragma unroll
    for (int kb = 0; kb < 2; ++kb)
#pragma unroll
      for (int q4 = 0; q4 < 4; ++q4)
#pragma unroll
        for (int p = 0; p < 2; ++p)
          pk[kb][q4][p] = pack_bf2(sa[kb][4 * q4 + 2 * p], sa[kb][4 * q4 + 2 * p + 1]);
    // ---- O^T += V^T P^T
#pragma unroll
    for (int kb16 = 0; kb16 < 4; ++kb16) {
      const int kb32 = kb16 >> 1;
      const int q4a = 2 * (kb16 & 1);
      const unsigned X0 = pk[kb32][q4a][0], X1 = pk[kb32][q4a][1];
      const unsigned Y0 = pk[kb32][q4a + 1][0], Y1 = pk[kb32][q4a + 1][1];
      const unsigned pX0 = __shfl_xor((int)X0, 32), pX1 = __shfl_xor((int)X1, 32);
      const unsigned pY0 = __shfl_xor((int)Y0, 32), pY1 = __shfl_xor((int)Y1, 32);
      u32x4 pw;
      pw[0] = hi5 ? pY0 : X0;
      pw[1] = hi5 ? pY1 : X1;
      pw[2] = hi5 ? Y0 : pX0;
      pw[3] = hi5 ? Y1 : pX1;
      const bf16x8 pf = __builtin_bit_cast(bf16x8, pw);
      __builtin_amdgcn_s_setprio(1);
#pragma unroll
      for (int hb = 0; hb < 2; ++hb)
        o[hb] = __builtin_amdgcn_mfma_f32_32x32x16_bf16(vf[kb16][hb], pf, o[hb], 0, 0, 0);
      __builtin_amdgcn_s_setprio(0);
    }
  }

  // ---- store partials: po bf16[32 q][64 h], pml f32[2][32]
  const size_t idx = (size_t)(b * 128 + s) * MAXC + c;
  bf16* po = part_o + idx * (32 * 64);
#pragma unroll
  for (int hb = 0; hb < 2; ++hb)
#pragma unroll
    for (int q4 = 0; q4 < 4; ++q4) {
      const int h0 = 32 * hb + 8 * q4 + 4 * hi5;
      ushort4 pk4;
      pk4.x = (unsigned short)f2bfs(o[hb][4 * q4 + 0]);
      pk4.y = (unsigned short)f2bfs(o[hb][4 * q4 + 1]);
      pk4.z = (unsigned short)f2bfs(o[hb][4 * q4 + 2]);
      pk4.w = (unsigned short)f2bfs(o[hb][4 * q4 + 3]);
      *reinterpret_cast<ushort4*>(po + (size_t)l31 * 64 + h0) = pk4;
    }
  if (hi5 == 0) {
    float* pml = part_ml + idx * 64;
    pml[l31] = m;
    pml[32 + l31] = lsum;
  }
}

// ---------------- kernel 2b: combine + normalize --------------------------
// grid NB*128*2 x 256 thr; block = 16 rows of a 32-row stripe.
__global__ __launch_bounds__(256) void k_attn_comb(const bf16* __restrict__ part_o,
                                                   const float* __restrict__ part_ml,
                                                   float* __restrict__ out,
                                                   int CH, int MAXC) {
  const int gid = blockIdx.x;
  const int rg = gid & 1;
  const int s = (gid >> 1) & 127;
  const int b = gid >> 8;
  const int row = rg * 16 + (threadIdx.x >> 4);
  const int cq = threadIdx.x & 15;
  const int ntiles = (s >> 1) + 1;
  const int nc = (ntiles + CH - 1) / CH;
  const size_t base = (size_t)(b * 128 + s) * MAXC;

  float M = -1e30f;
  for (int c = 0; c < nc; ++c)
    M = fmaxf(M, part_ml[(base + c) * 64 + row]);
  float L = 0.f, a0 = 0.f, a1 = 0.f, a2 = 0.f, a3 = 0.f;
  for (int c = 0; c < nc; ++c) {
    const float mc = part_ml[(base + c) * 64 + row];
    const float lc = part_ml[(base + c) * 64 + 32 + row];
    const float sc = exp2f(mc - M);
    L += lc * sc;
    ushort4 v = *reinterpret_cast<const ushort4*>(
        part_o + (base + c) * (32 * 64) + (size_t)row * 64 + cq * 4);
    a0 += bfs2f(v.x) * sc;
    a1 += bfs2f(v.y) * sc;
    a2 += bfs2f(v.z) * sc;
    a3 += bfs2f(v.w) * sc;
  }
  const float inv = 1.f / L;
  float4 ov;
  ov.x = a0 * inv; ov.y = a1 * inv; ov.z = a2 * inv; ov.w = a3 * inv;
  *reinterpret_cast<float4*>(
      out + (size_t)(b * NT + s * 32 + row) * NH + cq * 4) = ov;
}

// ---------------- launcher ------------------------------------------------
extern "C" void kernel_launch(void* const* d_in, const int* in_sizes, int n_in,
                              void* d_out, int out_size, void* d_ws, size_t ws_size,
                              hipStream_t stream) {
  const float* x  = (const float*)d_in[0];
  const float* Wk = (const float*)d_in[1];
  const float* Wq = (const float*)d_in[2];
  const float* Wv = (const float*)d_in[3];
  float* out = (float*)d_out;

  char* ws = (char*)d_ws;
  const size_t sz_wt  = (size_t)12 * 24 * 64 * 8 * sizeof(bf16);  // 294912
  const size_t sz_xb  = (size_t)NB * NT * NE * sizeof(bf16);      // 25.2 MB
  const size_t sz_qkv = (size_t)NB * NT * NH * sizeof(bf16);      // 2 MB
  const size_t off_xb = (sz_wt + 255) & ~size_t(255);
  const size_t off_q  = off_xb + sz_xb;
  const size_t off_k  = off_q + sz_qkv;
  const size_t off_vt = off_k + sz_qkv;
  const size_t off_pp = off_vt + sz_qkv;

  // per-unit partial: o bf16[32][64] (4 KB) + ml f32[2][32] (256 B)
  int CH = 64, MAXC = 1;
  const int opts_ch[4]   = {4, 8, 16, 64};
  const int opts_maxc[4] = {16, 8, 4, 1};
  for (int i = 0; i < 4; ++i) {
    const size_t n_idx = (size_t)NB * 128 * opts_maxc[i];
    const size_t need = off_pp + n_idx * (4096 + 256);
    if (ws_size >= need) { CH = opts_ch[i]; MAXC = opts_maxc[i]; break; }
  }
  const size_t n_idx = (size_t)NB * 128 * MAXC;
  const size_t off_po = off_pp;
  const size_t off_ml = off_po + n_idx * 4096;

  bf16* Wt2 = (bf16*)(ws);
  bf16* xb  = (bf16*)(ws + off_xb);
  bf16* Qw  = (bf16*)(ws + off_q);
  bf16* Kw  = (bf16*)(ws + off_k);
  bf16* Vtw = (bf16*)(ws + off_vt);
  bf16* part_o   = (bf16*)(ws + off_po);
  float* part_ml = (float*)(ws + off_ml);

  hipLaunchKernelGGL(k_prep, dim3(72 + NB * NT * NE / 2048), dim3(256), 0, stream,
                     x, Wk, Wq, Wv, Wt2, xb);
  hipLaunchKernelGGL(k_proj, dim3(NB * NT / 64, 3), dim3(256), 0, stream,
                     xb, Wt2, Qw, Kw, Vtw);
  hipLaunchKernelGGL(k_attn_part, dim3(NB * 128 * MAXC / 4), dim3(256), 0, stream,
                     Qw, Kw, Vtw, part_o, part_ml, CH, MAXC);
  hipLaunchKernelGGL(k_attn_comb, dim3(NB * 128 * 2), dim3(256), 0, stream,
                     part_o, part_ml, out, CH, MAXC);
}

// Round 7
// 162.095 us; speedup vs baseline: 1.1323x; 1.1043x over previous
//
#include <hip/hip_runtime.h>
#include <hip/hip_bf16.h>

#define NB 4
#define NT 4096
#define NE 768
#define NH 64

using bf16 = __hip_bfloat16;
typedef __attribute__((ext_vector_type(8))) short bf16x8;
typedef __attribute__((ext_vector_type(4))) float f32x4;
typedef __attribute__((ext_vector_type(16))) float f32x16;
typedef __attribute__((ext_vector_type(4))) unsigned int u32x4;

// softmax scale 1/8 with log2(e) folded -> exp2 everywhere
#define QSCALE 0.18033688011112042f /* 0.125 * log2(e) */

__device__ inline short f2bfs(float f) {
  bf16 h = __float2bfloat16(f);
  return __builtin_bit_cast(short, h);
}
__device__ inline float bfs2f(unsigned short u) {
  unsigned v = ((unsigned)u) << 16;
  return __builtin_bit_cast(float, v);
}
__device__ inline unsigned pack_bf2(float a, float b) {
  unsigned short ua = __builtin_bit_cast(unsigned short, __float2bfloat16(a));
  unsigned short ub = __builtin_bit_cast(unsigned short, __float2bfloat16(b));
  return ((unsigned)ub << 16) | ua;
}
// non-temporal 8B store (partials stream; don't evict K/V from L2/L3)
__device__ inline void nt_store8(void* p, ushort4 v) {
  __builtin_nontemporal_store(__builtin_bit_cast(unsigned long long, v),
                              (unsigned long long*)p);
}

#define GLOAD_LDS16(gsrc, ldst)                                        \
  __builtin_amdgcn_global_load_lds(                                    \
      (const __attribute__((address_space(1))) void*)(gsrc),           \
      (__attribute__((address_space(3))) void*)(ldst), 16, 0, 0)

// ---------------- kernel 0: W -> Wt2 fragment layout ----------------------
// Wt2[cbg][ks][lane][8]; j-th elem = W[ks*32+(lane>>4)*8+j][(cbg&3)*16+(lane&15)]
__global__ __launch_bounds__(256) void k_wt(const float* __restrict__ Wk,
                                            const float* __restrict__ Wq,
                                            const float* __restrict__ Wv,
                                            bf16* __restrict__ Wt2) {
  __shared__ float xl[32][65];
  const int m = blockIdx.x / 24;
  const int ks = blockIdx.x % 24;
  const int tid = threadIdx.x;
  const float* W = (m == 0) ? Wk : ((m == 1) ? Wq : Wv);
  const float scale = (m == 1) ? QSCALE : 1.0f;
  const int e0 = ks * 32;
#pragma unroll
  for (int i = 0; i < 8; ++i) {
    const int lin = i * 256 + tid;
    xl[lin >> 6][lin & 63] = W[(size_t)(e0 + (lin >> 6)) * NH + (lin & 63)];
  }
  __syncthreads();
  const int lane = tid & 63, w = tid >> 6;
  const int cbg = m * 4 + w;
  bf16x8 t;
#pragma unroll
  for (int j = 0; j < 8; ++j)
    t[j] = f2bfs(xl[((lane >> 4) << 3) + j][w * 16 + (lane & 15)] * scale);
  *reinterpret_cast<bf16x8*>(Wt2 + (((size_t)cbg * 24 + ks) * 64 + lane) * 8) = t;
}

// ---------------- kernel 1: fused Q/K/V projections -----------------------
// 512 blocks x 256 thr; block = 32-row x-stripe in LDS (swizzled, inline
// f32->bf16); wave w computes cbg w*3..w*3+2 for BOTH 16-row stripes
// (1 W-fragment load from L2 feeds 2 MFMAs).
__global__ __launch_bounds__(256) void k_proj(const float* __restrict__ x,
                                              const bf16* __restrict__ Wt2,
                                              bf16* __restrict__ Q,
                                              bf16* __restrict__ K,
                                              bf16* __restrict__ Vt) {
  __shared__ __align__(16) bf16 xl[32][768];  // 48 KB
  const int tid = threadIdx.x;
  const int wave = tid >> 6, lane = tid & 63;
  const int lr = lane & 15, lk = lane >> 4;
  const int row0 = blockIdx.x * 32;

#pragma unroll
  for (int j = 0; j < 12; ++j) {
    const int e = (j * 256 + tid) * 8;
    const int row = e / 768;
    const int col = e - row * 768;
    const int chunk = col >> 3;
    const int sch = (chunk & ~7) | ((chunk ^ row) & 7);
    const float* xp = x + (size_t)(row0 + row) * NE + col;
    float4 a0 = *reinterpret_cast<const float4*>(xp);
    float4 a1 = *reinterpret_cast<const float4*>(xp + 4);
    bf16x8 af;
    af[0] = f2bfs(a0.x); af[1] = f2bfs(a0.y); af[2] = f2bfs(a0.z); af[3] = f2bfs(a0.w);
    af[4] = f2bfs(a1.x); af[5] = f2bfs(a1.y); af[6] = f2bfs(a1.z); af[7] = f2bfs(a1.w);
    *reinterpret_cast<bf16x8*>((char*)xl + row * 1536 + sch * 16) = af;
  }
  __syncthreads();

  f32x4 acc0[3], acc1[3];
#pragma unroll
  for (int cb = 0; cb < 3; ++cb)
#pragma unroll
    for (int r = 0; r < 4; ++r) { acc0[cb][r] = 0.f; acc1[cb][r] = 0.f; }

#pragma unroll 4
  for (int ks = 0; ks < 24; ++ks) {
    const int chunk = ks * 4 + lk;
    const int sch = (chunk & ~7) | ((chunk ^ lr) & 7);  // (16+lr)&7 == lr&7
    bf16x8 af0 = *reinterpret_cast<const bf16x8*>((const char*)xl + lr * 1536 + sch * 16);
    bf16x8 af1 = *reinterpret_cast<const bf16x8*>((const char*)xl + (16 + lr) * 1536 + sch * 16);
#pragma unroll
    for (int cb = 0; cb < 3; ++cb) {
      bf16x8 bfr = *reinterpret_cast<const bf16x8*>(
          Wt2 + (((size_t)(wave * 3 + cb) * 24 + ks) * 64 + lane) * 8);
      acc0[cb] = __builtin_amdgcn_mfma_f32_16x16x32_bf16(af0, bfr, acc0[cb], 0, 0, 0);
      acc1[cb] = __builtin_amdgcn_mfma_f32_16x16x32_bf16(af1, bfr, acc1[cb], 0, 0, 0);
    }
  }

#pragma unroll
  for (int st = 0; st < 2; ++st) {
    const int trow = row0 + st * 16 + lk * 4;
#pragma unroll
    for (int cb = 0; cb < 3; ++cb) {
      const f32x4 a = st ? acc1[cb] : acc0[cb];
      const int hh0 = (wave * 3 + cb) * 16;
      const int m = hh0 >> 6;
      const int h = (hh0 & 63) + lr;
      if (m == 0) {
#pragma unroll
        for (int r = 0; r < 4; ++r)
          K[(size_t)(trow + r) * NH + h] = __float2bfloat16(a[r]);
      } else if (m == 1) {
#pragma unroll
        for (int r = 0; r < 4; ++r)
          Q[(size_t)(trow + r) * NH + h] = __float2bfloat16(a[r]);
      } else {
        const int bb = trow >> 12;
        const int t = trow & (NT - 1);
        ushort4 pk4;
        pk4.x = (unsigned short)f2bfs(a[0]);
        pk4.y = (unsigned short)f2bfs(a[1]);
        pk4.z = (unsigned short)f2bfs(a[2]);
        pk4.w = (unsigned short)f2bfs(a[3]);
        *reinterpret_cast<ushort4*>(Vt + (size_t)(bb * NH + h) * NT + t) = pk4;
      }
    }
  }
}

// ---------------- kernel 2a: split-KV flash attention ---------------------
// r4 structure (best measured): block = 4 waves x 32 q-rows = 128-row
// stripe; K/V 64-key tiles double-buffered via global_load_lds; one barrier
// per tile; swapped QK^T -> in-lane softmax; P in registers.
__device__ inline void stage_kv(const bf16* Kb, const bf16* Vb, int k0,
                                bf16* Kl, bf16* Vl, int wave, int lane) {
  const int rsub = lane >> 3, ch = lane & 7;
#pragma unroll
  for (int j = 0; j < 2; ++j) {
    const int br = j * 32 + wave * 8;
    const int row = br + rsub;
    const int sch = ch ^ (row & 7);
    GLOAD_LDS16(Kb + (size_t)(k0 + row) * NH + sch * 8, Kl + br * 64);
    GLOAD_LDS16(Vb + (size_t)row * NT + k0 + sch * 8, Vl + br * 64);
  }
}

__global__ __launch_bounds__(256) void k_attn_part(const bf16* __restrict__ Q,
                                                   const bf16* __restrict__ K,
                                                   const bf16* __restrict__ Vt,
                                                   bf16* __restrict__ part_o,
                                                   float* __restrict__ part_ml,
                                                   int CH, int MAXC) {
  __shared__ __align__(16) bf16 Kl[2][64][64];  // 16 KB
  __shared__ __align__(16) bf16 Vl[2][64][64];  // 16 KB
  const int tid = threadIdx.x;
  const int wave = tid >> 6, lane = tid & 63;
  const int l31 = lane & 31, hi5 = lane >> 5;
  const int gid = blockIdx.x;
  const int c = gid % MAXC;
  const int srs = (gid / MAXC) & 31;
  const int b = gid / (MAXC * 32);
  const int s = 31 - srs;  // big stripes dispatched first
  const int ntiles = 2 * s + 2;
  const int nch = (ntiles + CH - 1) / CH;
  if (c >= nch) return;  // block-uniform: whole block exits, no barrier risk
  const int kt0 = c * CH;
  const int kt1 = min(kt0 + CH, ntiles);
  const int qblk = s * 128;
  // interleaved q so all waves share the same causal diagonal profile
  const int qrow = 8 * wave + (l31 & 7) + 32 * (l31 >> 3);  // 0..127
  const int qcol = qblk + qrow;

  const bf16* Qb = Q + (size_t)(b * NT + qcol) * NH;
  const bf16* Kb = K + (size_t)b * NT * NH;
  const bf16* Vb = Vt + (size_t)b * NH * NT;

  bf16x8 qf[4];
#pragma unroll
  for (int ks = 0; ks < 4; ++ks)
    qf[ks] = *reinterpret_cast<const bf16x8*>(Qb + ks * 16 + hi5 * 8);

  f32x16 o[2];
#pragma unroll
  for (int hb = 0; hb < 2; ++hb)
#pragma unroll
    for (int r = 0; r < 16; ++r) o[hb][r] = 0.f;
  float m = -1e30f, lsum = 0.f;

  stage_kv(Kb, Vb, kt0 * 64, &Kl[0][0][0], &Vl[0][0][0], wave, lane);

  for (int kt = kt0; kt < kt1; ++kt) {
    const int buf = (kt - kt0) & 1;
    __syncthreads();  // drains staging vmcnt; buf ready, buf^1 reusable
    if (kt + 1 < kt1)
      stage_kv(Kb, Vb, (kt + 1) * 64, &Kl[buf ^ 1][0][0], &Vl[buf ^ 1][0][0], wave, lane);
    const int k0 = kt * 64;
    const bf16* Klb = &Kl[buf][0][0];
    const bf16* Vlb = &Vl[buf][0][0];

    // ---- S^T = K Q^T (D[key][q])
    f32x16 sa[2];
#pragma unroll
    for (int kb = 0; kb < 2; ++kb) {
#pragma unroll
      for (int r = 0; r < 16; ++r) sa[kb][r] = 0.f;
#pragma unroll
      for (int ks = 0; ks < 4; ++ks) {
        const int row = l31 + 32 * kb;
        const int sch = (hi5 + 2 * ks) ^ (row & 7);
        bf16x8 kf = *reinterpret_cast<const bf16x8*>(Klb + row * 64 + sch * 8);
        sa[kb] = __builtin_amdgcn_mfma_f32_32x32x16_bf16(kf, qf[ks], sa[kb], 0, 0, 0);
      }
    }
    // ---- causal mask (diagonal region only)
    if (kt >= 2 * s) {
#pragma unroll
      for (int kb = 0; kb < 2; ++kb)
#pragma unroll
        for (int r = 0; r < 16; ++r) {
          const int kg = k0 + (r & 3) + 8 * (r >> 2) + 4 * hi5 + 32 * kb;
          if (kg > qcol) sa[kb][r] = -1e30f;
        }
    }
    // ---- in-lane softmax (keys split across lane, lane^32)
    float t0[8];
#pragma unroll
    for (int r = 0; r < 8; ++r)
      t0[r] = fmaxf(fmaxf(sa[0][r], sa[0][r + 8]), fmaxf(sa[1][r], sa[1][r + 8]));
    float pm = fmaxf(fmaxf(fmaxf(t0[0], t0[1]), fmaxf(t0[2], t0[3])),
                     fmaxf(fmaxf(t0[4], t0[5]), fmaxf(t0[6], t0[7])));
    pm = fmaxf(pm, __shfl_xor(pm, 32));
    if (!__all(pm - m <= 6.f)) {  // defer-max: skip rescale when max stable
      const float mn = fmaxf(m, pm);
      const float alpha = exp2f(m - mn);
      lsum *= alpha;
#pragma unroll
      for (int hb = 0; hb < 2; ++hb)
#pragma unroll
        for (int r = 0; r < 16; ++r) o[hb][r] *= alpha;
      m = mn;
    }
    float rs0 = 0.f, rs1 = 0.f, rs2 = 0.f, rs3 = 0.f;
#pragma unroll
    for (int kb = 0; kb < 2; ++kb)
#pragma unroll
      for (int r = 0; r < 16; r += 4) {
        sa[kb][r] = exp2f(sa[kb][r] - m); rs0 += sa[kb][r];
        sa[kb][r + 1] = exp2f(sa[kb][r + 1] - m); rs1 += sa[kb][r + 1];
        sa[kb][r + 2] = exp2f(sa[kb][r + 2] - m); rs2 += sa[kb][r + 2];
        sa[kb][r + 3] = exp2f(sa[kb][r + 3] - m); rs3 += sa[kb][r + 3];
      }
    float rs = (rs0 + rs1) + (rs2 + rs3);
    rs += __shfl_xor(rs, 32);
    lsum += rs;
    // ---- pack P to bf16 pairs; redistribute halves via shfl_xor(32)
    unsigned pk[2][4][2];
#pragma unroll
    for (int kb = 0; kb < 2; ++kb)
#pragma unroll
      for (int q4 = 0; q4 < 4; ++q4)
#pragma unroll
        for (int p = 0; p < 2; ++p)
          pk[kb][q4][p] = pack_bf2(sa[kb][4 * q4 + 2 * p], sa[kb][4 * q4 + 2 * p + 1]);
    // ---- O^T += V^T P^T
#pragma unroll
    for (int kb16 = 0; kb16 < 4; ++kb16) {
      const int kb32 = kb16 >> 1;
      const int q4a = 2 * (kb16 & 1);
      const unsigned X0 = pk[kb32][q4a][0], X1 = pk[kb32][q4a][1];
      const unsigned Y0 = pk[kb32][q4a + 1][0], Y1 = pk[kb32][q4a + 1][1];
      const unsigned pX0 = __shfl_xor((int)X0, 32), pX1 = __shfl_xor((int)X1, 32);
      const unsigned pY0 = __shfl_xor((int)Y0, 32), pY1 = __shfl_xor((int)Y1, 32);
      u32x4 pw;
      pw[0] = hi5 ? pY0 : X0;
      pw[1] = hi5 ? pY1 : X1;
      pw[2] = hi5 ? Y0 : pX0;
      pw[3] = hi5 ? Y1 : pX1;
      const bf16x8 pf = __builtin_bit_cast(bf16x8, pw);
#pragma unroll
      for (int hb = 0; hb < 2; ++hb) {
        const int row = l31 + 32 * hb;
        const int sch = (hi5 + 2 * kb16) ^ (row & 7);
        bf16x8 vf = *reinterpret_cast<const bf16x8*>(Vlb + row * 64 + sch * 8);
        o[hb] = __builtin_amdgcn_mfma_f32_32x32x16_bf16(vf, pf, o[hb], 0, 0, 0);
      }
    }
  }

  // ---- store partials: po bf16[128 q][64 h] (non-temporal), pml f32[2][128]
  const size_t idx = (size_t)(b * 32 + s) * MAXC + c;
  bf16* po = part_o + idx * (128 * 64);
#pragma unroll
  for (int hb = 0; hb < 2; ++hb)
#pragma unroll
    for (int q4 = 0; q4 < 4; ++q4) {
      const int h0 = 32 * hb + 8 * q4 + 4 * hi5;
      ushort4 pk4;
      pk4.x = (unsigned short)f2bfs(o[hb][4 * q4 + 0]);
      pk4.y = (unsigned short)f2bfs(o[hb][4 * q4 + 1]);
      pk4.z = (unsigned short)f2bfs(o[hb][4 * q4 + 2]);
      pk4.w = (unsigned short)f2bfs(o[hb][4 * q4 + 3]);
      nt_store8(po + (size_t)qrow * 64 + h0, pk4);
    }
  if (hi5 == 0) {
    float* pml = part_ml + idx * 256;
    pml[qrow] = m;
    pml[128 + qrow] = lsum;
  }
}

// ---------------- kernel 2b: combine + normalize --------------------------
// grid NB*32*8 x 256 thr; block = 16 rows; thread = (row, 4-col group)
__global__ __launch_bounds__(256) void k_attn_comb(const bf16* __restrict__ part_o,
                                                   const float* __restrict__ part_ml,
                                                   float* __restrict__ out,
                                                   int CH, int MAXC) {
  const int gid = blockIdx.x;
  const int rg = gid & 7;
  const int s = (gid >> 3) & 31;
  const int b = gid >> 8;
  const int row = rg * 16 + (threadIdx.x >> 4);
  const int cq = threadIdx.x & 15;
  const int ntiles = 2 * s + 2;
  const int nc = (ntiles + CH - 1) / CH;
  const size_t base = (size_t)(b * 32 + s) * MAXC;

  float M = -1e30f;
  for (int c = 0; c < nc; ++c)
    M = fmaxf(M, part_ml[(base + c) * 256 + row]);
  float L = 0.f, a0 = 0.f, a1 = 0.f, a2 = 0.f, a3 = 0.f;
  for (int c = 0; c < nc; ++c) {
    const float mc = part_ml[(base + c) * 256 + row];
    const float lc = part_ml[(base + c) * 256 + 128 + row];
    const float sc = exp2f(mc - M);
    L += lc * sc;
    ushort4 v = *reinterpret_cast<const ushort4*>(
        part_o + (base + c) * (128 * 64) + (size_t)row * 64 + cq * 4);
    a0 += bfs2f(v.x) * sc;
    a1 += bfs2f(v.y) * sc;
    a2 += bfs2f(v.z) * sc;
    a3 += bfs2f(v.w) * sc;
  }
  const float inv = 1.f / L;
  float4 ov;
  ov.x = a0 * inv; ov.y = a1 * inv; ov.z = a2 * inv; ov.w = a3 * inv;
  *reinterpret_cast<float4*>(
      out + (size_t)(b * NT + s * 128 + row) * NH + cq * 4) = ov;
}

// ---------------- launcher ------------------------------------------------
extern "C" void kernel_launch(void* const* d_in, const int* in_sizes, int n_in,
                              void* d_out, int out_size, void* d_ws, size_t ws_size,
                              hipStream_t stream) {
  const float* x  = (const float*)d_in[0];
  const float* Wk = (const float*)d_in[1];
  const float* Wq = (const float*)d_in[2];
  const float* Wv = (const float*)d_in[3];
  float* out = (float*)d_out;

  char* ws = (char*)d_ws;
  const size_t sz_wt  = (size_t)12 * 24 * 64 * 8 * sizeof(bf16);  // 294912
  const size_t sz_qkv = (size_t)NB * NT * NH * sizeof(bf16);      // 2 MB
  const size_t off_q  = (sz_wt + 255) & ~size_t(255);
  const size_t off_k  = off_q + sz_qkv;
  const size_t off_vt = off_k + sz_qkv;
  const size_t off_pp = off_vt + sz_qkv;

  // per-chunk partial: o bf16[128][64] (16 KB) + ml f32[2][128] (1 KB)
  const size_t per_chunk = (size_t)128 * 64 * sizeof(bf16) + 256 * sizeof(float);
  int CH = 64, MAXC = 1;
  const int opts_ch[4]   = {4, 6, 8, 16};
  const int opts_maxc[4] = {16, 11, 8, 4};
  for (int i = 0; i < 4; ++i) {
    const size_t need = off_pp + (size_t)NB * 32 * opts_maxc[i] * per_chunk;
    if (ws_size >= need) { CH = opts_ch[i]; MAXC = opts_maxc[i]; break; }
  }
  const size_t n_idx = (size_t)NB * 32 * MAXC;
  const size_t off_po = off_pp;
  const size_t off_ml = off_po + n_idx * (size_t)(128 * 64) * sizeof(bf16);

  bf16* Wt2 = (bf16*)(ws);
  bf16* Qw  = (bf16*)(ws + off_q);
  bf16* Kw  = (bf16*)(ws + off_k);
  bf16* Vtw = (bf16*)(ws + off_vt);
  bf16* part_o   = (bf16*)(ws + off_po);
  float* part_ml = (float*)(ws + off_ml);

  hipLaunchKernelGGL(k_wt, dim3(3 * 24), dim3(256), 0, stream, Wk, Wq, Wv, Wt2);
  hipLaunchKernelGGL(k_proj, dim3(NB * NT / 32), dim3(256), 0, stream,
                     x, Wt2, Qw, Kw, Vtw);
  hipLaunchKernelGGL(k_attn_part, dim3(NB * 32 * MAXC), dim3(256), 0, stream,
                     Qw, Kw, Vtw, part_o, part_ml, CH, MAXC);
  hipLaunchKernelGGL(k_attn_comb, dim3(NB * 32 * 8), dim3(256), 0, stream,
                     part_o, part_ml, out, CH, MAXC);
}

// Round 8
// 150.416 us; speedup vs baseline: 1.2202x; 1.0776x over previous
//
#include <hip/hip_runtime.h>
#include <hip/hip_bf16.h>

#define NB 4
#define NT 4096
#define NE 768
#define NH 64

using bf16 = __hip_bfloat16;
typedef __attribute__((ext_vector_type(8))) short bf16x8;
typedef __attribute__((ext_vector_type(4))) float f32x4;
typedef __attribute__((ext_vector_type(16))) float f32x16;
typedef __attribute__((ext_vector_type(4))) unsigned int u32x4;

// softmax scale 1/8 with log2(e) folded -> exp2 everywhere
#define QSCALE 0.18033688011112042f /* 0.125 * log2(e) */

__device__ inline short f2bfs(float f) {
  bf16 h = __float2bfloat16(f);
  return __builtin_bit_cast(short, h);
}
__device__ inline float bfs2f(unsigned short u) {
  unsigned v = ((unsigned)u) << 16;
  return __builtin_bit_cast(float, v);
}
__device__ inline unsigned pack_bf2(float a, float b) {
  unsigned short ua = __builtin_bit_cast(unsigned short, __float2bfloat16(a));
  unsigned short ub = __builtin_bit_cast(unsigned short, __float2bfloat16(b));
  return ((unsigned)ub << 16) | ua;
}
// non-temporal 8B store (partials stream; don't evict K/V from L2/L3)
__device__ inline void nt_store8(void* p, ushort4 v) {
  __builtin_nontemporal_store(__builtin_bit_cast(unsigned long long, v),
                              (unsigned long long*)p);
}

#define GLOAD_LDS16(gsrc, ldst)                                        \
  __builtin_amdgcn_global_load_lds(                                    \
      (const __attribute__((address_space(1))) void*)(gsrc),           \
      (__attribute__((address_space(3))) void*)(ldst), 16, 0, 0)

// ---------------- kernel 0: W -> Wt2 fragment layout ----------------------
// Wt2[cbg][ks][lane][8]; j-th elem = W[ks*32+(lane>>4)*8+j][(cbg&3)*16+(lane&15)]
__global__ __launch_bounds__(256) void k_wt(const float* __restrict__ Wk,
                                            const float* __restrict__ Wq,
                                            const float* __restrict__ Wv,
                                            bf16* __restrict__ Wt2) {
  __shared__ float xl[32][65];
  const int m = blockIdx.x / 24;
  const int ks = blockIdx.x % 24;
  const int tid = threadIdx.x;
  const float* W = (m == 0) ? Wk : ((m == 1) ? Wq : Wv);
  const float scale = (m == 1) ? QSCALE : 1.0f;
  const int e0 = ks * 32;
#pragma unroll
  for (int i = 0; i < 8; ++i) {
    const int lin = i * 256 + tid;
    xl[lin >> 6][lin & 63] = W[(size_t)(e0 + (lin >> 6)) * NH + (lin & 63)];
  }
  __syncthreads();
  const int lane = tid & 63, w = tid >> 6;
  const int cbg = m * 4 + w;
  bf16x8 t;
#pragma unroll
  for (int j = 0; j < 8; ++j)
    t[j] = f2bfs(xl[((lane >> 4) << 3) + j][w * 16 + (lane & 15)] * scale);
  *reinterpret_cast<bf16x8*>(Wt2 + (((size_t)cbg * 24 + ks) * 64 + lane) * 8) = t;
}

// ---------------- kernel 1: fused Q/K/V projections -----------------------
// 512 blocks x 256 thr; block = 32-row x-stripe in LDS (swizzled, inline
// f32->bf16); wave w computes cbg w*3..w*3+2 for BOTH 16-row stripes.
__global__ __launch_bounds__(256) void k_proj(const float* __restrict__ x,
                                              const bf16* __restrict__ Wt2,
                                              bf16* __restrict__ Q,
                                              bf16* __restrict__ K,
                                              bf16* __restrict__ Vt) {
  __shared__ __align__(16) bf16 xl[32][768];  // 48 KB
  const int tid = threadIdx.x;
  const int wave = tid >> 6, lane = tid & 63;
  const int lr = lane & 15, lk = lane >> 4;
  const int row0 = blockIdx.x * 32;

#pragma unroll
  for (int j = 0; j < 12; ++j) {
    const int e = (j * 256 + tid) * 8;
    const int row = e / 768;
    const int col = e - row * 768;
    const int chunk = col >> 3;
    const int sch = (chunk & ~7) | ((chunk ^ row) & 7);
    const float* xp = x + (size_t)(row0 + row) * NE + col;
    float4 a0 = *reinterpret_cast<const float4*>(xp);
    float4 a1 = *reinterpret_cast<const float4*>(xp + 4);
    bf16x8 af;
    af[0] = f2bfs(a0.x); af[1] = f2bfs(a0.y); af[2] = f2bfs(a0.z); af[3] = f2bfs(a0.w);
    af[4] = f2bfs(a1.x); af[5] = f2bfs(a1.y); af[6] = f2bfs(a1.z); af[7] = f2bfs(a1.w);
    *reinterpret_cast<bf16x8*>((char*)xl + row * 1536 + sch * 16) = af;
  }
  __syncthreads();

  f32x4 acc0[3], acc1[3];
#pragma unroll
  for (int cb = 0; cb < 3; ++cb)
#pragma unroll
    for (int r = 0; r < 4; ++r) { acc0[cb][r] = 0.f; acc1[cb][r] = 0.f; }

#pragma unroll 4
  for (int ks = 0; ks < 24; ++ks) {
    const int chunk = ks * 4 + lk;
    const int sch = (chunk & ~7) | ((chunk ^ lr) & 7);  // (16+lr)&7 == lr&7
    bf16x8 af0 = *reinterpret_cast<const bf16x8*>((const char*)xl + lr * 1536 + sch * 16);
    bf16x8 af1 = *reinterpret_cast<const bf16x8*>((const char*)xl + (16 + lr) * 1536 + sch * 16);
#pragma unroll
    for (int cb = 0; cb < 3; ++cb) {
      bf16x8 bfr = *reinterpret_cast<const bf16x8*>(
          Wt2 + (((size_t)(wave * 3 + cb) * 24 + ks) * 64 + lane) * 8);
      acc0[cb] = __builtin_amdgcn_mfma_f32_16x16x32_bf16(af0, bfr, acc0[cb], 0, 0, 0);
      acc1[cb] = __builtin_amdgcn_mfma_f32_16x16x32_bf16(af1, bfr, acc1[cb], 0, 0, 0);
    }
  }

#pragma unroll
  for (int st = 0; st < 2; ++st) {
    const int trow = row0 + st * 16 + lk * 4;
#pragma unroll
    for (int cb = 0; cb < 3; ++cb) {
      const f32x4 a = st ? acc1[cb] : acc0[cb];
      const int hh0 = (wave * 3 + cb) * 16;
      const int m = hh0 >> 6;
      const int h = (hh0 & 63) + lr;
      if (m == 0) {
#pragma unroll
        for (int r = 0; r < 4; ++r)
          K[(size_t)(trow + r) * NH + h] = __float2bfloat16(a[r]);
      } else if (m == 1) {
#pragma unroll
        for (int r = 0; r < 4; ++r)
          Q[(size_t)(trow + r) * NH + h] = __float2bfloat16(a[r]);
      } else {
        const int bb = trow >> 12;
        const int t = trow & (NT - 1);
        ushort4 pk4;
        pk4.x = (unsigned short)f2bfs(a[0]);
        pk4.y = (unsigned short)f2bfs(a[1]);
        pk4.z = (unsigned short)f2bfs(a[2]);
        pk4.w = (unsigned short)f2bfs(a[3]);
        *reinterpret_cast<ushort4*>(Vt + (size_t)(bb * NH + h) * NT + t) = pk4;
      }
    }
  }
}

// ---------------- kernel 2a: split-KV flash attention ---------------------
// EXACT grid: every block is an active (b, stripe s, chunk c) unit — the
// whole grid is co-resident (≤5 blocks/CU by LDS), so independent blocks'
// serial chains overlap. 4 waves x 32 q-rows; K/V dbuf via global_load_lds.
__device__ inline void stage_kv(const bf16* Kb, const bf16* Vb, int k0,
                                bf16* Kl, bf16* Vl, int wave, int lane) {
  const int rsub = lane >> 3, ch = lane & 7;
#pragma unroll
  for (int j = 0; j < 2; ++j) {
    const int br = j * 32 + wave * 8;
    const int row = br + rsub;
    const int sch = ch ^ (row & 7);
    GLOAD_LDS16(Kb + (size_t)(k0 + row) * NH + sch * 8, Kl + br * 64);
    GLOAD_LDS16(Vb + (size_t)row * NT + k0 + sch * 8, Vl + br * 64);
  }
}

__global__ __launch_bounds__(256, 4) void k_attn_part(const bf16* __restrict__ Q,
                                                      const bf16* __restrict__ K,
                                                      const bf16* __restrict__ Vt,
                                                      bf16* __restrict__ part_o,
                                                      float* __restrict__ part_ml,
                                                      int CH, int MAXC, int NCHB) {
  __shared__ __align__(16) bf16 Kl[2][64][64];  // 16 KB
  __shared__ __align__(16) bf16 Vl[2][64][64];  // 16 KB
  const int tid = threadIdx.x;
  const int wave = tid >> 6, lane = tid & 63;
  const int l31 = lane & 31, hi5 = lane >> 5;
  // ---- exact work mapping: gid -> (b, s, c); big s first
  const int gid = blockIdx.x;
  const int b = gid / NCHB;
  int u = gid - b * NCHB;
  int s = 31;
  for (;;) {
    const int nch = (2 * s + 2 + CH - 1) / CH;
    if (u < nch) break;
    u -= nch;
    --s;
  }
  const int c = u;
  const int ntiles = 2 * s + 2;
  const int kt0 = c * CH;
  const int kt1 = min(kt0 + CH, ntiles);
  const int qblk = s * 128;
  // interleaved q so all waves share the same causal diagonal profile
  const int qrow = 8 * wave + (l31 & 7) + 32 * (l31 >> 3);  // 0..127
  const int qcol = qblk + qrow;

  const bf16* Qb = Q + (size_t)(b * NT + qcol) * NH;
  const bf16* Kb = K + (size_t)b * NT * NH;
  const bf16* Vb = Vt + (size_t)b * NH * NT;

  bf16x8 qf[4];
#pragma unroll
  for (int ks = 0; ks < 4; ++ks)
    qf[ks] = *reinterpret_cast<const bf16x8*>(Qb + ks * 16 + hi5 * 8);

  f32x16 o[2];
#pragma unroll
  for (int hb = 0; hb < 2; ++hb)
#pragma unroll
    for (int r = 0; r < 16; ++r) o[hb][r] = 0.f;
  float m = -1e30f, lsum = 0.f;

  stage_kv(Kb, Vb, kt0 * 64, &Kl[0][0][0], &Vl[0][0][0], wave, lane);

  for (int kt = kt0; kt < kt1; ++kt) {
    const int buf = (kt - kt0) & 1;
    __syncthreads();  // drains staging vmcnt; buf ready, buf^1 reusable
    if (kt + 1 < kt1)
      stage_kv(Kb, Vb, (kt + 1) * 64, &Kl[buf ^ 1][0][0], &Vl[buf ^ 1][0][0], wave, lane);
    const int k0 = kt * 64;
    const bf16* Klb = &Kl[buf][0][0];
    const bf16* Vlb = &Vl[buf][0][0];

    // ---- S^T = K Q^T (D[key][q])
    f32x16 sa[2];
#pragma unroll
    for (int kb = 0; kb < 2; ++kb) {
#pragma unroll
      for (int r = 0; r < 16; ++r) sa[kb][r] = 0.f;
#pragma unroll
      for (int ks = 0; ks < 4; ++ks) {
        const int row = l31 + 32 * kb;
        const int sch = (hi5 + 2 * ks) ^ (row & 7);
        bf16x8 kf = *reinterpret_cast<const bf16x8*>(Klb + row * 64 + sch * 8);
        sa[kb] = __builtin_amdgcn_mfma_f32_32x32x16_bf16(kf, qf[ks], sa[kb], 0, 0, 0);
      }
    }
    // ---- causal mask (diagonal region only)
    if (kt >= 2 * s) {
#pragma unroll
      for (int kb = 0; kb < 2; ++kb)
#pragma unroll
        for (int r = 0; r < 16; ++r) {
          const int kg = k0 + (r & 3) + 8 * (r >> 2) + 4 * hi5 + 32 * kb;
          if (kg > qcol) sa[kb][r] = -1e30f;
        }
    }
    // ---- in-lane softmax (keys split across lane, lane^32)
    float t0[8];
#pragma unroll
    for (int r = 0; r < 8; ++r)
      t0[r] = fmaxf(fmaxf(sa[0][r], sa[0][r + 8]), fmaxf(sa[1][r], sa[1][r + 8]));
    float pm = fmaxf(fmaxf(fmaxf(t0[0], t0[1]), fmaxf(t0[2], t0[3])),
                     fmaxf(fmaxf(t0[4], t0[5]), fmaxf(t0[6], t0[7])));
    pm = fmaxf(pm, __shfl_xor(pm, 32));
    if (!__all(pm - m <= 6.f)) {  // defer-max: skip rescale when max stable
      const float mn = fmaxf(m, pm);
      const float alpha = exp2f(m - mn);
      lsum *= alpha;
#pragma unroll
      for (int hb = 0; hb < 2; ++hb)
#pragma unroll
        for (int r = 0; r < 16; ++r) o[hb][r] *= alpha;
      m = mn;
    }
    float rs0 = 0.f, rs1 = 0.f, rs2 = 0.f, rs3 = 0.f;
#pragma unroll
    for (int kb = 0; kb < 2; ++kb)
#pragma unroll
      for (int r = 0; r < 16; r += 4) {
        sa[kb][r] = exp2f(sa[kb][r] - m); rs0 += sa[kb][r];
        sa[kb][r + 1] = exp2f(sa[kb][r + 1] - m); rs1 += sa[kb][r + 1];
        sa[kb][r + 2] = exp2f(sa[kb][r + 2] - m); rs2 += sa[kb][r + 2];
        sa[kb][r + 3] = exp2f(sa[kb][r + 3] - m); rs3 += sa[kb][r + 3];
      }
    float rs = (rs0 + rs1) + (rs2 + rs3);
    rs += __shfl_xor(rs, 32);
    lsum += rs;
    // ---- pack P to bf16 pairs; redistribute halves via shfl_xor(32)
    unsigned pk[2][4][2];
#pragma unroll
    for (int kb = 0; kb < 2; ++kb)
#pragma unroll
      for (int q4 = 0; q4 < 4; ++q4)
#pragma unroll
        for (int p = 0; p < 2; ++p)
          pk[kb][q4][p] = pack_bf2(sa[kb][4 * q4 + 2 * p], sa[kb][4 * q4 + 2 * p + 1]);
    // ---- O^T += V^T P^T
#pragma unroll
    for (int kb16 = 0; kb16 < 4; ++kb16) {
      const int kb32 = kb16 >> 1;
      const int q4a = 2 * (kb16 & 1);
      const unsigned X0 = pk[kb32][q4a][0], X1 = pk[kb32][q4a][1];
      const unsigned Y0 = pk[kb32][q4a + 1][0], Y1 = pk[kb32][q4a + 1][1];
      const unsigned pX0 = __shfl_xor((int)X0, 32), pX1 = __shfl_xor((int)X1, 32);
      const unsigned pY0 = __shfl_xor((int)Y0, 32), pY1 = __shfl_xor((int)Y1, 32);
      u32x4 pw;
      pw[0] = hi5 ? pY0 : X0;
      pw[1] = hi5 ? pY1 : X1;
      pw[2] = hi5 ? Y0 : pX0;
      pw[3] = hi5 ? Y1 : pX1;
      const bf16x8 pf = __builtin_bit_cast(bf16x8, pw);
#pragma unroll
      for (int hb = 0; hb < 2; ++hb) {
        const int row = l31 + 32 * hb;
        const int sch = (hi5 + 2 * kb16) ^ (row & 7);
        bf16x8 vf = *reinterpret_cast<const bf16x8*>(Vlb + row * 64 + sch * 8);
        o[hb] = __builtin_amdgcn_mfma_f32_32x32x16_bf16(vf, pf, o[hb], 0, 0, 0);
      }
    }
  }

  // ---- store partials: po bf16[128 q][64 h] (non-temporal), pml f32[2][128]
  const size_t idx = (size_t)(b * 32 + s) * MAXC + c;
  bf16* po = part_o + idx * (128 * 64);
#pragma unroll
  for (int hb = 0; hb < 2; ++hb)
#pragma unroll
    for (int q4 = 0; q4 < 4; ++q4) {
      const int h0 = 32 * hb + 8 * q4 + 4 * hi5;
      ushort4 pk4;
      pk4.x = (unsigned short)f2bfs(o[hb][4 * q4 + 0]);
      pk4.y = (unsigned short)f2bfs(o[hb][4 * q4 + 1]);
      pk4.z = (unsigned short)f2bfs(o[hb][4 * q4 + 2]);
      pk4.w = (unsigned short)f2bfs(o[hb][4 * q4 + 3]);
      nt_store8(po + (size_t)qrow * 64 + h0, pk4);
    }
  if (hi5 == 0) {
    float* pml = part_ml + idx * 256;
    pml[qrow] = m;
    pml[128 + qrow] = lsum;
  }
}

// ---------------- kernel 2b: combine + normalize --------------------------
// grid NB*32*8 x 256 thr; block = 16 rows; thread = (row, 4-col group)
__global__ __launch_bounds__(256) void k_attn_comb(const bf16* __restrict__ part_o,
                                                   const float* __restrict__ part_ml,
                                                   float* __restrict__ out,
                                                   int CH, int MAXC) {
  const int gid = blockIdx.x;
  const int rg = gid & 7;
  const int s = (gid >> 3) & 31;
  const int b = gid >> 8;
  const int row = rg * 16 + (threadIdx.x >> 4);
  const int cq = threadIdx.x & 15;
  const int ntiles = 2 * s + 2;
  const int nc = (ntiles + CH - 1) / CH;
  const size_t base = (size_t)(b * 32 + s) * MAXC;

  float M = -1e30f;
  for (int c = 0; c < nc; ++c)
    M = fmaxf(M, part_ml[(base + c) * 256 + row]);
  float L = 0.f, a0 = 0.f, a1 = 0.f, a2 = 0.f, a3 = 0.f;
  for (int c = 0; c < nc; ++c) {
    const float mc = part_ml[(base + c) * 256 + row];
    const float lc = part_ml[(base + c) * 256 + 128 + row];
    const float sc = exp2f(mc - M);
    L += lc * sc;
    ushort4 v = *reinterpret_cast<const ushort4*>(
        part_o + (base + c) * (128 * 64) + (size_t)row * 64 + cq * 4);
    a0 += bfs2f(v.x) * sc;
    a1 += bfs2f(v.y) * sc;
    a2 += bfs2f(v.z) * sc;
    a3 += bfs2f(v.w) * sc;
  }
  const float inv = 1.f / L;
  float4 ov;
  ov.x = a0 * inv; ov.y = a1 * inv; ov.z = a2 * inv; ov.w = a3 * inv;
  *reinterpret_cast<float4*>(
      out + (size_t)(b * NT + s * 128 + row) * NH + cq * 4) = ov;
}

// ---------------- launcher ------------------------------------------------
extern "C" void kernel_launch(void* const* d_in, const int* in_sizes, int n_in,
                              void* d_out, int out_size, void* d_ws, size_t ws_size,
                              hipStream_t stream) {
  const float* x  = (const float*)d_in[0];
  const float* Wk = (const float*)d_in[1];
  const float* Wq = (const float*)d_in[2];
  const float* Wv = (const float*)d_in[3];
  float* out = (float*)d_out;

  char* ws = (char*)d_ws;
  const size_t sz_wt  = (size_t)12 * 24 * 64 * 8 * sizeof(bf16);  // 294912
  const size_t sz_qkv = (size_t)NB * NT * NH * sizeof(bf16);      // 2 MB
  const size_t off_q  = (sz_wt + 255) & ~size_t(255);
  const size_t off_k  = off_q + sz_qkv;
  const size_t off_vt = off_k + sz_qkv;
  const size_t off_pp = off_vt + sz_qkv;

  // per-chunk partial: o bf16[128][64] (16 KB) + ml f32[2][128] (1 KB)
  const size_t per_chunk = (size_t)128 * 64 * sizeof(bf16) + 256 * sizeof(float);
  int CH = 64, MAXC = 1;
  const int opts_ch[4]   = {6, 8, 16, 64};
  const int opts_maxc[4] = {11, 8, 4, 1};
  for (int i = 0; i < 4; ++i) {
    const size_t need = off_pp + (size_t)NB * 32 * opts_maxc[i] * per_chunk;
    if (ws_size >= need) { CH = opts_ch[i]; MAXC = opts_maxc[i]; break; }
  }
  // exact active-chunk count per batch
  int NCHB = 0;
  for (int s = 0; s < 32; ++s) NCHB += (2 * s + 2 + CH - 1) / CH;

  const size_t n_idx = (size_t)NB * 32 * MAXC;
  const size_t off_po = off_pp;
  const size_t off_ml = off_po + n_idx * (size_t)(128 * 64) * sizeof(bf16);

  bf16* Wt2 = (bf16*)(ws);
  bf16* Qw  = (bf16*)(ws + off_q);
  bf16* Kw  = (bf16*)(ws + off_k);
  bf16* Vtw = (bf16*)(ws + off_vt);
  bf16* part_o   = (bf16*)(ws + off_po);
  float* part_ml = (float*)(ws + off_ml);

  hipLaunchKernelGGL(k_wt, dim3(3 * 24), dim3(256), 0, stream, Wk, Wq, Wv, Wt2);
  hipLaunchKernelGGL(k_proj, dim3(NB * NT / 32), dim3(256), 0, stream,
                     x, Wt2, Qw, Kw, Vtw);
  hipLaunchKernelGGL(k_attn_part, dim3(NB * NCHB), dim3(256), 0, stream,
                     Qw, Kw, Vtw, part_o, part_ml, CH, MAXC, NCHB);
  hipLaunchKernelGGL(k_attn_comb, dim3(NB * 32 * 8), dim3(256), 0, stream,
                     part_o, part_ml, out, CH, MAXC);
}